// Round 1
// baseline (2281.329 us; speedup 1.0000x reference)
//
#include <hip/hip_runtime.h>
#include <math.h>

#define D_MODEL 1024
#define D_STATE 32
#define D_INNER 2048
#define DT_RANK 64
#define BT 4096            // B*T = 2*2048
#define LN_EPS 1e-5f

// ---------------------------------------------------------------- LayerNorm
__global__ __launch_bounds__(256) void ln_kernel(const float* __restrict__ x,
                                                 const float* __restrict__ g,
                                                 const float* __restrict__ b,
                                                 float* __restrict__ xn) {
    int row = blockIdx.x;
    const float4* xr = (const float4*)(x + (size_t)row * D_MODEL);
    float4 v = xr[threadIdx.x];
    float s  = v.x + v.y + v.z + v.w;
    float ss = v.x*v.x + v.y*v.y + v.z*v.z + v.w*v.w;
    #pragma unroll
    for (int off = 32; off > 0; off >>= 1) {
        s  += __shfl_down(s,  off, 64);
        ss += __shfl_down(ss, off, 64);
    }
    __shared__ float rs[4], rss[4];
    int wave = threadIdx.x >> 6;
    if ((threadIdx.x & 63) == 0) { rs[wave] = s; rss[wave] = ss; }
    __syncthreads();
    s  = rs[0] + rs[1] + rs[2] + rs[3];
    ss = rss[0] + rss[1] + rss[2] + rss[3];
    float mu  = s * (1.f / D_MODEL);
    float var = ss * (1.f / D_MODEL) - mu * mu;
    float inv = rsqrtf(var + LN_EPS);
    float4 gv = ((const float4*)g)[threadIdx.x];
    float4 bv = ((const float4*)b)[threadIdx.x];
    float4 o;
    o.x = (v.x - mu) * inv * gv.x + bv.x;
    o.y = (v.y - mu) * inv * gv.y + bv.y;
    o.z = (v.z - mu) * inv * gv.z + bv.z;
    o.w = (v.w - mu) * inv * gv.w + bv.w;
    ((float4*)(xn + (size_t)row * D_MODEL))[threadIdx.x] = o;
}

// ------------------------------------------------- generic fp32 NT GEMM
// C[M,N] = A[M,K(lda)] * B[N,K(ldb)]^T  (+bias[col]) (ACT=1: softplus) (+resid)
// 64x64 block tile, BK=16, 256 threads, 4x4 micro-tile. M,N %64==0, K %16==0.
template<int ACT>
__global__ __launch_bounds__(256) void gemm_nt(const float* __restrict__ A, int lda,
                                               const float* __restrict__ B, int ldb,
                                               float* __restrict__ C, int ldc,
                                               int K,
                                               const float* __restrict__ bias,
                                               const float* __restrict__ resid) {
    __shared__ float As[16][68];   // [k][m], stride 68: store conflicts 2-way (free)
    __shared__ float Bs[16][68];   // [k][n]
    int tid = threadIdx.x;
    int bm = blockIdx.x * 64;
    int bn = blockIdx.y * 64;
    int tx = tid & 15, ty = tid >> 4;
    int lr = tid >> 2;             // 0..63
    int lk = (tid & 3) << 2;       // 0,4,8,12
    const float* Ap = A + (size_t)(bm + lr) * lda + lk;
    const float* Bp = B + (size_t)(bn + lr) * ldb + lk;
    float acc[4][4] = {};
    for (int k0 = 0; k0 < K; k0 += 16) {
        float4 a4 = *(const float4*)(Ap + k0);
        float4 b4 = *(const float4*)(Bp + k0);
        As[lk+0][lr] = a4.x; As[lk+1][lr] = a4.y; As[lk+2][lr] = a4.z; As[lk+3][lr] = a4.w;
        Bs[lk+0][lr] = b4.x; Bs[lk+1][lr] = b4.y; Bs[lk+2][lr] = b4.z; Bs[lk+3][lr] = b4.w;
        __syncthreads();
        #pragma unroll
        for (int k = 0; k < 16; ++k) {
            float4 av = *(const float4*)&As[k][ty << 2];
            float4 bv = *(const float4*)&Bs[k][tx << 2];
            float ar[4] = {av.x, av.y, av.z, av.w};
            float br[4] = {bv.x, bv.y, bv.z, bv.w};
            #pragma unroll
            for (int i = 0; i < 4; ++i)
                #pragma unroll
                for (int j = 0; j < 4; ++j)
                    acc[i][j] = fmaf(ar[i], br[j], acc[i][j]);
        }
        __syncthreads();
    }
    #pragma unroll
    for (int i = 0; i < 4; ++i) {
        int row = bm + (ty << 2) + i;
        #pragma unroll
        for (int j = 0; j < 4; ++j) {
            int col = bn + (tx << 2) + j;
            float v = acc[i][j];
            if (bias)  v += bias[col];
            if (ACT == 1) v = (v > 20.f) ? v : log1pf(expf(v));
            if (resid) v += resid[(size_t)row * ldc + col];
            C[(size_t)row * ldc + col] = v;
        }
    }
}

// ---------------------------------------------------------------- scan
// One thread per (b, e, s). Block = 256 threads = 8 e-values x 32 states.
// Grid = 2 * (2048/8) = 512 blocks. Serial over t; y-reduction over s via
// 32-wide shuffles; gating (y + D*x) * z * sigmoid(z) fused.
__global__ __launch_bounds__(256) void scan_kernel(
    const float* __restrict__ xz,     // [BT, 4096]  (x_ssm | z)
    const float* __restrict__ xdbl,   // [BT, 128]   (dt_low | B | C)
    const float* __restrict__ dt,     // [BT, 2048]
    const float* __restrict__ A_log_real,  // [2048, 32]
    const float* __restrict__ A_imag,      // [2048, 32]
    const float* __restrict__ D_param,     // [2048]
    float* __restrict__ y)            // [BT, 2048]
{
    int s  = threadIdx.x & 31;
    int el = threadIdx.x >> 5;                 // 0..7
    int b  = blockIdx.x >> 8;                  // 256 blocks per batch
    int e  = ((blockIdx.x & 255) << 3) + el;   // 0..2047
    float Ar = -expf(A_log_real[e * D_STATE + s]);
    float Ai = A_imag[e * D_STATE + s];
    float Dp = D_param[e];
    float hr = 0.f, hi = 0.f;
    const float* xzb = xz   + (size_t)b * 2048 * 4096;
    const float* xdb = xdbl + (size_t)b * 2048 * 128;
    const float* dtb = dt   + (size_t)b * 2048 * 2048;
    float*       yb  = y    + (size_t)b * 2048 * 2048;
    for (int t = 0; t < 2048; ++t) {
        float dtv = dtb[(size_t)t * 2048 + e];
        float xv  = xzb[(size_t)t * 4096 + e];
        float zv  = xzb[(size_t)t * 4096 + 2048 + e];
        float Bv  = xdb[t * 128 + DT_RANK + s];
        float Cv  = xdb[t * 128 + DT_RANK + D_STATE + s];
        float scale = expf(Ar * dtv);
        float ang = Ai * dtv;
        float sa, ca;
        sincosf(ang, &sa, &ca);
        float dAr = scale * ca, dAi = scale * sa;
        float dBx = dtv * xv * Bv;
        float hr2 = dAr * hr - dAi * hi + dBx;
        float hi2 = dAr * hi + dAi * hr;
        hr = hr2; hi = hi2;
        float p = hr * Cv;
        p += __shfl_xor(p, 16, 32);
        p += __shfl_xor(p, 8, 32);
        p += __shfl_xor(p, 4, 32);
        p += __shfl_xor(p, 2, 32);
        p += __shfl_xor(p, 1, 32);
        if (s == 0) {
            float yv  = p + Dp * xv;
            float sig = 1.f / (1.f + expf(-zv));
            yb[(size_t)t * 2048 + e] = yv * zv * sig;
        }
    }
}

// ---------------------------------------------------------------- launch
extern "C" void kernel_launch(void* const* d_in, const int* in_sizes, int n_in,
                              void* d_out, int out_size, void* d_ws, size_t ws_size,
                              hipStream_t stream) {
    const float* x          = (const float*)d_in[0];
    const float* W_in       = (const float*)d_in[1];
    const float* W_x        = (const float*)d_in[2];
    const float* W_dt       = (const float*)d_in[3];
    const float* b_dt       = (const float*)d_in[4];
    const float* A_log_real = (const float*)d_in[5];
    const float* A_imag     = (const float*)d_in[6];
    const float* D_param    = (const float*)d_in[7];
    const float* W_out      = (const float*)d_in[8];
    const float* ln_g       = (const float*)d_in[9];
    const float* ln_b       = (const float*)d_in[10];
    float* out = (float*)d_out;

    char* ws = (char*)d_ws;
    float* xz   = (float*)(ws);                          // 64 MB: [4096,4096]
    float* dt   = (float*)(ws + ((size_t)64 << 20));     // 32 MB: [4096,2048]
    float* xdbl = (float*)(ws + ((size_t)96 << 20));     //  2 MB: [4096,128]
    float* xn   = (float*)(ws + ((size_t)98 << 20));     // 16 MB: [4096,1024]
    float* y    = (float*)(ws + ((size_t)98 << 20));     // 32 MB, overlaps xn (dead)

    // 1. LayerNorm
    ln_kernel<<<BT, 256, 0, stream>>>(x, ln_g, ln_b, xn);
    // 2. xz = xn @ W_in^T   [4096,4096]
    gemm_nt<0><<<dim3(BT/64, 4096/64), 256, 0, stream>>>(
        xn, D_MODEL, W_in, D_MODEL, xz, 4096, D_MODEL, nullptr, nullptr);
    // 3. x_dbl = x_ssm @ W_x^T   [4096,128]  (x_ssm = xz[:, :2048], lda=4096)
    gemm_nt<0><<<dim3(BT/64, 128/64), 256, 0, stream>>>(
        xz, 4096, W_x, D_INNER, xdbl, 128, D_INNER, nullptr, nullptr);
    // 4. dt = softplus(dt_low @ W_dt^T + b_dt)   [4096,2048] (dt_low: lda=128, K=64)
    gemm_nt<1><<<dim3(BT/64, D_INNER/64), 256, 0, stream>>>(
        xdbl, 128, W_dt, DT_RANK, dt, D_INNER, DT_RANK, b_dt, nullptr);
    // 5. scan + gating -> y   [4096,2048]
    scan_kernel<<<512, 256, 0, stream>>>(xz, xdbl, dt, A_log_real, A_imag, D_param, y);
    // 6. out = residual + y @ W_out^T   [4096,1024]
    gemm_nt<0><<<dim3(BT/64, D_MODEL/64), 256, 0, stream>>>(
        y, D_INNER, W_out, D_INNER, out, D_MODEL, D_INNER, nullptr, x);
}

// Round 2
// 2158.659 us; speedup vs baseline: 1.0568x; 1.0568x over previous
//
#include <hip/hip_runtime.h>
#include <math.h>

#define D_MODEL 1024
#define D_STATE 32
#define D_INNER 2048
#define DT_RANK 64
#define BT 4096            // B*T = 2*2048
#define LN_EPS 1e-5f

typedef __attribute__((ext_vector_type(8))) short short8;
typedef __attribute__((ext_vector_type(4))) float f32x4;

__device__ __forceinline__ ushort bf16r(float f) {
    unsigned u = __float_as_uint(f);
    u += 0x7fff + ((u >> 16) & 1);          // round-to-nearest-even
    return (ushort)(u >> 16);
}

// ---------------------------------------------------------------- fp32 -> bf16
__global__ __launch_bounds__(256) void cvt_bf16(const float* __restrict__ in,
                                                ushort* __restrict__ out, int n4) {
    int i = blockIdx.x * 256 + threadIdx.x;
    if (i >= n4) return;
    float4 v = ((const float4*)in)[i];
    ushort4 o;
    o.x = bf16r(v.x); o.y = bf16r(v.y); o.z = bf16r(v.z); o.w = bf16r(v.w);
    ((ushort4*)out)[i] = o;
}

// ---------------------------------------------------------------- LayerNorm -> bf16
__global__ __launch_bounds__(256) void ln_kernel(const float* __restrict__ x,
                                                 const float* __restrict__ g,
                                                 const float* __restrict__ b,
                                                 ushort* __restrict__ xn) {
    int row = blockIdx.x;
    const float4* xr = (const float4*)(x + (size_t)row * D_MODEL);
    float4 v = xr[threadIdx.x];
    float s  = v.x + v.y + v.z + v.w;
    float ss = v.x*v.x + v.y*v.y + v.z*v.z + v.w*v.w;
    #pragma unroll
    for (int off = 32; off > 0; off >>= 1) {
        s  += __shfl_down(s,  off, 64);
        ss += __shfl_down(ss, off, 64);
    }
    __shared__ float rs[4], rss[4];
    int wave = threadIdx.x >> 6;
    if ((threadIdx.x & 63) == 0) { rs[wave] = s; rss[wave] = ss; }
    __syncthreads();
    s  = rs[0] + rs[1] + rs[2] + rs[3];
    ss = rss[0] + rss[1] + rss[2] + rss[3];
    float mu  = s * (1.f / D_MODEL);
    float var = ss * (1.f / D_MODEL) - mu * mu;
    float inv = rsqrtf(var + LN_EPS);
    float4 gv = ((const float4*)g)[threadIdx.x];
    float4 bv = ((const float4*)b)[threadIdx.x];
    ushort4 o;
    o.x = bf16r((v.x - mu) * inv * gv.x + bv.x);
    o.y = bf16r((v.y - mu) * inv * gv.y + bv.y);
    o.z = bf16r((v.z - mu) * inv * gv.z + bv.z);
    o.w = bf16r((v.w - mu) * inv * gv.w + bv.w);
    ((ushort4*)(xn + (size_t)row * D_MODEL))[threadIdx.x] = o;
}

// ------------------------------------------------- bf16 MFMA NT GEMM
// C[M,N] = A[M,K] * B[N,K]^T (+resid), A/B bf16 row-major, C fp32.
// 128x128 tile, BK=32, 256 threads = 4 waves (2x2 of 64x64).
template<int RESID>
__global__ __launch_bounds__(256) void gemm_bt_bf16(
    const ushort* __restrict__ A, const ushort* __restrict__ B,
    float* __restrict__ C, int ldc, int K,
    const float* __restrict__ resid)
{
    __shared__ __align__(16) ushort As[128 * 32];   // [m][k] dense
    __shared__ __align__(16) ushort Bs[128 * 32];   // [n][k] dense
    int tid = threadIdx.x;
    int bm = blockIdx.x * 128, bn = blockIdx.y * 128;
    int wave = tid >> 6, lane = tid & 63;
    int wm = (wave & 1) * 64, wn = (wave >> 1) * 64;
    int quad = lane >> 4, m16 = lane & 15;
    int srow = tid >> 2;             // 0..63
    int schunk = (tid & 3) * 8;      // k elem offset (16 B chunks)

    f32x4 acc[4][4] = {};
    for (int k0 = 0; k0 < K; k0 += 32) {
        #pragma unroll
        for (int p = 0; p < 2; ++p) {
            int r = srow + p * 64;
            *(ulonglong2*)&As[r * 32 + schunk] =
                *(const ulonglong2*)&A[(size_t)(bm + r) * K + k0 + schunk];
            *(ulonglong2*)&Bs[r * 32 + schunk] =
                *(const ulonglong2*)&B[(size_t)(bn + r) * K + k0 + schunk];
        }
        __syncthreads();
        short8 af[4], bf[4];
        #pragma unroll
        for (int i = 0; i < 4; ++i)
            af[i] = *(const short8*)&As[(wm + i * 16 + m16) * 32 + quad * 8];
        #pragma unroll
        for (int j = 0; j < 4; ++j)
            bf[j] = *(const short8*)&Bs[(wn + j * 16 + m16) * 32 + quad * 8];
        #pragma unroll
        for (int i = 0; i < 4; ++i)
            #pragma unroll
            for (int j = 0; j < 4; ++j)
                acc[i][j] = __builtin_amdgcn_mfma_f32_16x16x32_bf16(
                    af[i], bf[j], acc[i][j], 0, 0, 0);
        __syncthreads();
    }
    #pragma unroll
    for (int i = 0; i < 4; ++i) {
        #pragma unroll
        for (int r = 0; r < 4; ++r) {
            int row = bm + wm + i * 16 + quad * 4 + r;
            #pragma unroll
            for (int j = 0; j < 4; ++j) {
                int col = bn + wn + j * 16 + m16;
                float v = acc[i][j][r];
                if (RESID) v += resid[(size_t)row * ldc + col];
                C[(size_t)row * ldc + col] = v;
            }
        }
    }
}

// ------------------------------------------------- generic fp32 NT GEMM (small ops)
template<int ACT>
__global__ __launch_bounds__(256) void gemm_nt(const float* __restrict__ A, int lda,
                                               const float* __restrict__ B, int ldb,
                                               float* __restrict__ C, int ldc,
                                               int K,
                                               const float* __restrict__ bias) {
    __shared__ float As[16][68];
    __shared__ float Bs[16][68];
    int tid = threadIdx.x;
    int bm = blockIdx.x * 64;
    int bn = blockIdx.y * 64;
    int tx = tid & 15, ty = tid >> 4;
    int lr = tid >> 2;
    int lk = (tid & 3) << 2;
    const float* Ap = A + (size_t)(bm + lr) * lda + lk;
    const float* Bp = B + (size_t)(bn + lr) * ldb + lk;
    float acc[4][4] = {};
    for (int k0 = 0; k0 < K; k0 += 16) {
        float4 a4 = *(const float4*)(Ap + k0);
        float4 b4 = *(const float4*)(Bp + k0);
        As[lk+0][lr] = a4.x; As[lk+1][lr] = a4.y; As[lk+2][lr] = a4.z; As[lk+3][lr] = a4.w;
        Bs[lk+0][lr] = b4.x; Bs[lk+1][lr] = b4.y; Bs[lk+2][lr] = b4.z; Bs[lk+3][lr] = b4.w;
        __syncthreads();
        #pragma unroll
        for (int k = 0; k < 16; ++k) {
            float4 av = *(const float4*)&As[k][ty << 2];
            float4 bv = *(const float4*)&Bs[k][tx << 2];
            float ar[4] = {av.x, av.y, av.z, av.w};
            float br[4] = {bv.x, bv.y, bv.z, bv.w};
            #pragma unroll
            for (int i = 0; i < 4; ++i)
                #pragma unroll
                for (int j = 0; j < 4; ++j)
                    acc[i][j] = fmaf(ar[i], br[j], acc[i][j]);
        }
        __syncthreads();
    }
    #pragma unroll
    for (int i = 0; i < 4; ++i) {
        int row = bm + (ty << 2) + i;
        #pragma unroll
        for (int j = 0; j < 4; ++j) {
            int col = bn + (tx << 2) + j;
            float v = acc[i][j];
            if (bias)  v += bias[col];
            if (ACT == 1) v = (v > 20.f) ? v : __logf(1.f + __expf(v));
            C[(size_t)row * ldc + col] = v;
        }
    }
}

// ---------------------------------------------------------------- scan (+gate) -> bf16
__global__ __launch_bounds__(256) void scan_kernel(
    const float* __restrict__ xz,     // [BT, 4096]  (x_ssm | z)
    const float* __restrict__ xdbl,   // [BT, 128]   (dt_low | B | C)
    const float* __restrict__ dt,     // [BT, 2048]
    const float* __restrict__ A_log_real,
    const float* __restrict__ A_imag,
    const float* __restrict__ D_param,
    ushort* __restrict__ y)           // [BT, 2048] bf16
{
    int s  = threadIdx.x & 31;
    int el = threadIdx.x >> 5;
    int b  = blockIdx.x >> 8;
    int e  = ((blockIdx.x & 255) << 3) + el;
    float Ar = -__expf(A_log_real[e * D_STATE + s]);
    float Ai = A_imag[e * D_STATE + s];
    float Dp = D_param[e];
    float hr = 0.f, hi = 0.f;
    const float* xzb = xz   + (size_t)b * 2048 * 4096;
    const float* xdb = xdbl + (size_t)b * 2048 * 128;
    const float* dtb = dt   + (size_t)b * 2048 * 2048;
    ushort*      yb  = y    + (size_t)b * 2048 * 2048;
    #pragma unroll 4
    for (int t = 0; t < 2048; ++t) {
        float dtv = dtb[(size_t)t * 2048 + e];
        float xv  = xzb[(size_t)t * 4096 + e];
        float zv  = xzb[(size_t)t * 4096 + 2048 + e];
        float Bv  = xdb[t * 128 + DT_RANK + s];
        float Cv  = xdb[t * 128 + DT_RANK + D_STATE + s];
        float scale = __expf(Ar * dtv);
        float ang = Ai * dtv;
        float sa = __sinf(ang);
        float ca = __cosf(ang);
        float dAr = scale * ca, dAi = scale * sa;
        float dBx = dtv * xv * Bv;
        float hr2 = dAr * hr - dAi * hi + dBx;
        float hi2 = dAr * hi + dAi * hr;
        hr = hr2; hi = hi2;
        float p = hr * Cv;
        p += __shfl_xor(p, 16, 32);
        p += __shfl_xor(p, 8, 32);
        p += __shfl_xor(p, 4, 32);
        p += __shfl_xor(p, 2, 32);
        p += __shfl_xor(p, 1, 32);
        if (s == 0) {
            float yv  = p + Dp * xv;
            float sig = 1.f / (1.f + __expf(-zv));
            yb[(size_t)t * 2048 + e] = bf16r(yv * zv * sig);
        }
    }
}

// ---------------------------------------------------------------- launch
extern "C" void kernel_launch(void* const* d_in, const int* in_sizes, int n_in,
                              void* d_out, int out_size, void* d_ws, size_t ws_size,
                              hipStream_t stream) {
    const float* x          = (const float*)d_in[0];
    const float* W_in       = (const float*)d_in[1];
    const float* W_x        = (const float*)d_in[2];
    const float* W_dt       = (const float*)d_in[3];
    const float* b_dt       = (const float*)d_in[4];
    const float* A_log_real = (const float*)d_in[5];
    const float* A_imag     = (const float*)d_in[6];
    const float* D_param    = (const float*)d_in[7];
    const float* W_out      = (const float*)d_in[8];
    const float* ln_g       = (const float*)d_in[9];
    const float* ln_b       = (const float*)d_in[10];
    float* out = (float*)d_out;

    char* ws = (char*)d_ws;
    float*  xz      = (float*) (ws);                        // 64 MB [4096,4096]
    float*  dt      = (float*) (ws + ((size_t) 64 << 20));  // 32 MB [4096,2048]
    float*  xdbl    = (float*) (ws + ((size_t) 96 << 20));  //  2 MB [4096,128]
    ushort* xn_bf   = (ushort*)(ws + ((size_t) 98 << 20));  //  8 MB [4096,1024]
    ushort* Win_bf  = (ushort*)(ws + ((size_t)106 << 20));  //  8 MB [4096,1024] (dead after GEMM1)
    ushort* y_bf    = (ushort*)(ws + ((size_t)106 << 20));  // 16 MB [4096,2048] overlaps Win_bf
    ushort* Wout_bf = (ushort*)(ws + ((size_t)122 << 20));  //  4 MB [1024,2048]

    // weight conversions
    cvt_bf16<<<(4096*1024/4 + 255)/256, 256, 0, stream>>>(W_in,  Win_bf,  4096*1024/4);
    cvt_bf16<<<(1024*2048/4 + 255)/256, 256, 0, stream>>>(W_out, Wout_bf, 1024*2048/4);
    // 1. LayerNorm -> bf16
    ln_kernel<<<BT, 256, 0, stream>>>(x, ln_g, ln_b, xn_bf);
    // 2. xz = xn @ W_in^T   [4096,4096]  (bf16 MFMA)
    gemm_bt_bf16<0><<<dim3(BT/128, 4096/128), 256, 0, stream>>>(
        xn_bf, Win_bf, xz, 4096, D_MODEL, nullptr);
    // 3. x_dbl = x_ssm @ W_x^T   [4096,128]  (fp32)
    gemm_nt<0><<<dim3(BT/64, 128/64), 256, 0, stream>>>(
        xz, 4096, W_x, D_INNER, xdbl, 128, D_INNER, nullptr);
    // 4. dt = softplus(dt_low @ W_dt^T + b_dt)   [4096,2048]  (fp32)
    gemm_nt<1><<<dim3(BT/64, D_INNER/64), 256, 0, stream>>>(
        xdbl, 128, W_dt, DT_RANK, dt, D_INNER, DT_RANK, b_dt);
    // 5. scan + gating -> y (bf16)
    scan_kernel<<<512, 256, 0, stream>>>(xz, xdbl, dt, A_log_real, A_imag, D_param, y_bf);
    // 6. out = residual + y @ W_out^T   [4096,1024]  (bf16 MFMA + resid)
    gemm_bt_bf16<1><<<dim3(BT/128, D_MODEL/128), 256, 0, stream>>>(
        y_bf, Wout_bf, out, D_MODEL, D_INNER, x);
}

// Round 3
// 912.858 us; speedup vs baseline: 2.4991x; 2.3647x over previous
//
#include <hip/hip_runtime.h>
#include <math.h>

#define D_MODEL 1024
#define D_STATE 32
#define D_INNER 2048
#define DT_RANK 64
#define BT 4096            // B*T = 2*2048
#define LN_EPS 1e-5f

typedef __attribute__((ext_vector_type(8))) short short8;
typedef __attribute__((ext_vector_type(4))) float f32x4;

__device__ __forceinline__ ushort bf16r(float f) {
    unsigned u = __float_as_uint(f);
    u += 0x7fff + ((u >> 16) & 1);          // round-to-nearest-even
    return (ushort)(u >> 16);
}
__device__ __forceinline__ float bf2f(ushort h) {
    return __uint_as_float(((unsigned)h) << 16);
}

// ---------------------------------------------------------------- fp32 -> bf16
__global__ __launch_bounds__(256) void cvt_bf16(const float* __restrict__ in,
                                                ushort* __restrict__ out, int n4) {
    int i = blockIdx.x * 256 + threadIdx.x;
    if (i >= n4) return;
    float4 v = ((const float4*)in)[i];
    ushort4 o;
    o.x = bf16r(v.x); o.y = bf16r(v.y); o.z = bf16r(v.z); o.w = bf16r(v.w);
    ((ushort4*)out)[i] = o;
}

// ---------------------------------------------------------------- LayerNorm -> bf16
__global__ __launch_bounds__(256) void ln_kernel(const float* __restrict__ x,
                                                 const float* __restrict__ g,
                                                 const float* __restrict__ b,
                                                 ushort* __restrict__ xn) {
    int row = blockIdx.x;
    const float4* xr = (const float4*)(x + (size_t)row * D_MODEL);
    float4 v = xr[threadIdx.x];
    float s  = v.x + v.y + v.z + v.w;
    float ss = v.x*v.x + v.y*v.y + v.z*v.z + v.w*v.w;
    #pragma unroll
    for (int off = 32; off > 0; off >>= 1) {
        s  += __shfl_down(s,  off, 64);
        ss += __shfl_down(ss, off, 64);
    }
    __shared__ float rs[4], rss[4];
    int wave = threadIdx.x >> 6;
    if ((threadIdx.x & 63) == 0) { rs[wave] = s; rss[wave] = ss; }
    __syncthreads();
    s  = rs[0] + rs[1] + rs[2] + rs[3];
    ss = rss[0] + rss[1] + rss[2] + rss[3];
    float mu  = s * (1.f / D_MODEL);
    float var = ss * (1.f / D_MODEL) - mu * mu;
    float inv = rsqrtf(var + LN_EPS);
    float4 gv = ((const float4*)g)[threadIdx.x];
    float4 bv = ((const float4*)b)[threadIdx.x];
    ushort4 o;
    o.x = bf16r((v.x - mu) * inv * gv.x + bv.x);
    o.y = bf16r((v.y - mu) * inv * gv.y + bv.y);
    o.z = bf16r((v.z - mu) * inv * gv.z + bv.z);
    o.w = bf16r((v.w - mu) * inv * gv.w + bv.w);
    ((ushort4*)(xn + (size_t)row * D_MODEL))[threadIdx.x] = o;
}

// ------------------------------------------------- bf16 MFMA NT GEMM
template<int RESID>
__global__ __launch_bounds__(256) void gemm_bt_bf16(
    const ushort* __restrict__ A, const ushort* __restrict__ B,
    float* __restrict__ C, int ldc, int K,
    const float* __restrict__ resid)
{
    __shared__ __align__(16) ushort As[128 * 32];   // [m][k] dense
    __shared__ __align__(16) ushort Bs[128 * 32];   // [n][k] dense
    int tid = threadIdx.x;
    int bm = blockIdx.x * 128, bn = blockIdx.y * 128;
    int wave = tid >> 6, lane = tid & 63;
    int wm = (wave & 1) * 64, wn = (wave >> 1) * 64;
    int quad = lane >> 4, m16 = lane & 15;
    int srow = tid >> 2;
    int schunk = (tid & 3) * 8;

    f32x4 acc[4][4] = {};
    for (int k0 = 0; k0 < K; k0 += 32) {
        #pragma unroll
        for (int p = 0; p < 2; ++p) {
            int r = srow + p * 64;
            *(ulonglong2*)&As[r * 32 + schunk] =
                *(const ulonglong2*)&A[(size_t)(bm + r) * K + k0 + schunk];
            *(ulonglong2*)&Bs[r * 32 + schunk] =
                *(const ulonglong2*)&B[(size_t)(bn + r) * K + k0 + schunk];
        }
        __syncthreads();
        short8 af[4], bf[4];
        #pragma unroll
        for (int i = 0; i < 4; ++i)
            af[i] = *(const short8*)&As[(wm + i * 16 + m16) * 32 + quad * 8];
        #pragma unroll
        for (int j = 0; j < 4; ++j)
            bf[j] = *(const short8*)&Bs[(wn + j * 16 + m16) * 32 + quad * 8];
        #pragma unroll
        for (int i = 0; i < 4; ++i)
            #pragma unroll
            for (int j = 0; j < 4; ++j)
                acc[i][j] = __builtin_amdgcn_mfma_f32_16x16x32_bf16(
                    af[i], bf[j], acc[i][j], 0, 0, 0);
        __syncthreads();
    }
    #pragma unroll
    for (int i = 0; i < 4; ++i) {
        #pragma unroll
        for (int r = 0; r < 4; ++r) {
            int row = bm + wm + i * 16 + quad * 4 + r;
            #pragma unroll
            for (int j = 0; j < 4; ++j) {
                int col = bn + wn + j * 16 + m16;
                float v = acc[i][j][r];
                if (RESID) v += resid[(size_t)row * ldc + col];
                C[(size_t)row * ldc + col] = v;
            }
        }
    }
}

// ------------------------------------------------- generic fp32 NT GEMM (small ops)
template<int ACT>
__global__ __launch_bounds__(256) void gemm_nt(const float* __restrict__ A, int lda,
                                               const float* __restrict__ B, int ldb,
                                               float* __restrict__ C, int ldc,
                                               int K,
                                               const float* __restrict__ bias) {
    __shared__ float As[16][68];
    __shared__ float Bs[16][68];
    int tid = threadIdx.x;
    int bm = blockIdx.x * 64;
    int bn = blockIdx.y * 64;
    int tx = tid & 15, ty = tid >> 4;
    int lr = tid >> 2;
    int lk = (tid & 3) << 2;
    const float* Ap = A + (size_t)(bm + lr) * lda + lk;
    const float* Bp = B + (size_t)(bn + lr) * ldb + lk;
    float acc[4][4] = {};
    for (int k0 = 0; k0 < K; k0 += 16) {
        float4 a4 = *(const float4*)(Ap + k0);
        float4 b4 = *(const float4*)(Bp + k0);
        As[lk+0][lr] = a4.x; As[lk+1][lr] = a4.y; As[lk+2][lr] = a4.z; As[lk+3][lr] = a4.w;
        Bs[lk+0][lr] = b4.x; Bs[lk+1][lr] = b4.y; Bs[lk+2][lr] = b4.z; Bs[lk+3][lr] = b4.w;
        __syncthreads();
        #pragma unroll
        for (int k = 0; k < 16; ++k) {
            float4 av = *(const float4*)&As[k][ty << 2];
            float4 bv = *(const float4*)&Bs[k][tx << 2];
            float ar[4] = {av.x, av.y, av.z, av.w};
            float br[4] = {bv.x, bv.y, bv.z, bv.w};
            #pragma unroll
            for (int i = 0; i < 4; ++i)
                #pragma unroll
                for (int j = 0; j < 4; ++j)
                    acc[i][j] = fmaf(ar[i], br[j], acc[i][j]);
        }
        __syncthreads();
    }
    #pragma unroll
    for (int i = 0; i < 4; ++i) {
        int row = bm + (ty << 2) + i;
        #pragma unroll
        for (int j = 0; j < 4; ++j) {
            int col = bn + (tx << 2) + j;
            float v = acc[i][j];
            if (bias)  v += bias[col];
            if (ACT == 1) v = (v > 20.f) ? v : __logf(1.f + __expf(v));
            C[(size_t)row * ldc + col] = v;
        }
    }
}

// ---------------------------------------------------------------- scan v3
// Chunk-staged (T_CHUNK=32, double-buffered LDS). Block = 256 threads =
// 8 e x 32 states; grid 512. Gating moved to gate_kernel. Output: raw
// reduced p = sum_s hr*C as bf16.
__global__ __launch_bounds__(256) void scan_kernel(
    const float* __restrict__ xz,     // [BT, 4096]  (x_ssm | z)
    const float* __restrict__ xdbl,   // [BT, 128]   (dt_low | B | C)
    const float* __restrict__ dt,     // [BT, 2048]
    const float* __restrict__ A_log_real,
    const float* __restrict__ A_imag,
    ushort* __restrict__ y)           // [BT, 2048] bf16 (raw p)
{
    const int tid = threadIdx.x;
    const int s  = tid & 31;
    const int el = tid >> 5;                   // 0..7
    const int b  = blockIdx.x >> 8;
    const int e0 = (blockIdx.x & 255) << 3;
    const int e  = e0 + el;
    const int stt = tid >> 3;                  // 0..31 (t in chunk)
    const int see = tid & 7;                   // 0..7  (e in block)

    __shared__ __align__(16) float dxc[2][32][8][2];   // {dt, x}
    __shared__ __align__(16) float bcc[2][32][64];     // interleaved {B,C} per s

    float Ar = -__expf(A_log_real[e * D_STATE + s]);
    float Ai = A_imag[e * D_STATE + s];
    float hr = 0.f, hi = 0.f;
    const float* xzb = xz   + (size_t)b * 2048 * 4096;
    const float* xdb = xdbl + (size_t)b * 2048 * 128;
    const float* dtb = dt   + (size_t)b * 2048 * 2048;
    ushort*      yb  = y    + (size_t)b * 2048 * 2048;

    float r_dt, r_x;
    float4 r_b, r_c;
    // prologue: chunk 0
    {
        r_dt = dtb[(size_t)stt * 2048 + e0 + see];
        r_x  = xzb[(size_t)stt * 4096 + e0 + see];
        const float* p = xdb + (size_t)stt * 128 + DT_RANK + see * 4;
        r_b = *(const float4*)p;
        r_c = *(const float4*)(p + D_STATE);
        dxc[0][stt][see][0] = r_dt;
        dxc[0][stt][see][1] = r_x;
        #pragma unroll
        for (int k = 0; k < 4; ++k) {
            bcc[0][stt][2*(see*4+k)  ] = ((const float*)&r_b)[k];
            bcc[0][stt][2*(see*4+k)+1] = ((const float*)&r_c)[k];
        }
    }
    for (int c = 0; c < 64; ++c) {
        const int buf = c & 1;
        __syncthreads();
        if (c < 63) {               // issue next chunk's global loads early
            int t0n = (c + 1) * 32;
            r_dt = dtb[(size_t)(t0n + stt) * 2048 + e0 + see];
            r_x  = xzb[(size_t)(t0n + stt) * 4096 + e0 + see];
            const float* p = xdb + (size_t)(t0n + stt) * 128 + DT_RANK + see * 4;
            r_b = *(const float4*)p;
            r_c = *(const float4*)(p + D_STATE);
        }
        const int t0 = c * 32;
        #pragma unroll 8
        for (int tt = 0; tt < 32; ++tt) {
            float dtv = dxc[buf][tt][el][0];
            float xv  = dxc[buf][tt][el][1];
            float2 bc = *(const float2*)&bcc[buf][tt][2 * s];
            float scale = __expf(Ar * dtv);
            float ang = Ai * dtv;
            float sa = __sinf(ang);
            float ca = __cosf(ang);
            float dAr = scale * ca, dAi = scale * sa;
            float dBx = dtv * xv * bc.x;
            float hr2 = dAr * hr - dAi * hi + dBx;
            hi = dAr * hi + dAi * hr;
            hr = hr2;
            float p = hr * bc.y;
            p += __shfl_xor(p, 16, 32);
            p += __shfl_xor(p, 8, 32);
            p += __shfl_xor(p, 4, 32);
            p += __shfl_xor(p, 2, 32);
            p += __shfl_xor(p, 1, 32);
            if (s == 0)
                yb[(size_t)(t0 + tt) * 2048 + e] = bf16r(p);
        }
        if (c < 63) {
            const int nb = buf ^ 1;
            dxc[nb][stt][see][0] = r_dt;
            dxc[nb][stt][see][1] = r_x;
            #pragma unroll
            for (int k = 0; k < 4; ++k) {
                bcc[nb][stt][2*(see*4+k)  ] = ((const float*)&r_b)[k];
                bcc[nb][stt][2*(see*4+k)+1] = ((const float*)&r_c)[k];
            }
        }
    }
}

// ---------------------------------------------------------------- gate
// y = (p + D*x) * z * sigmoid(z), in-place on p (bf16). 4 elems/thread.
__global__ __launch_bounds__(256) void gate_kernel(
    ushort* __restrict__ p,           // [BT, 2048] bf16, in-place
    const float* __restrict__ xz,     // [BT, 4096]
    const float* __restrict__ D_param)
{
    int i = blockIdx.x * 256 + threadIdx.x;    // 0 .. 4096*512
    int bt = i >> 9;
    int e4 = (i & 511) << 2;
    float4 xv = *(const float4*)&xz[(size_t)bt * 4096 + e4];
    float4 zv = *(const float4*)&xz[(size_t)bt * 4096 + 2048 + e4];
    float4 Dv = *(const float4*)&D_param[e4];
    ushort4 pv = ((const ushort4*)p)[(size_t)i];
    float py[4] = {bf2f(pv.x), bf2f(pv.y), bf2f(pv.z), bf2f(pv.w)};
    float xs[4] = {xv.x, xv.y, xv.z, xv.w};
    float zs[4] = {zv.x, zv.y, zv.z, zv.w};
    float Ds[4] = {Dv.x, Dv.y, Dv.z, Dv.w};
    ushort4 o;
    ushort* op = (ushort*)&o;
    #pragma unroll
    for (int k = 0; k < 4; ++k) {
        float sig = 1.f / (1.f + __expf(-zs[k]));
        op[k] = bf16r((py[k] + Ds[k] * xs[k]) * zs[k] * sig);
    }
    ((ushort4*)p)[(size_t)i] = o;
}

// ---------------------------------------------------------------- launch
extern "C" void kernel_launch(void* const* d_in, const int* in_sizes, int n_in,
                              void* d_out, int out_size, void* d_ws, size_t ws_size,
                              hipStream_t stream) {
    const float* x          = (const float*)d_in[0];
    const float* W_in       = (const float*)d_in[1];
    const float* W_x        = (const float*)d_in[2];
    const float* W_dt       = (const float*)d_in[3];
    const float* b_dt       = (const float*)d_in[4];
    const float* A_log_real = (const float*)d_in[5];
    const float* A_imag     = (const float*)d_in[6];
    const float* D_param    = (const float*)d_in[7];
    const float* W_out      = (const float*)d_in[8];
    const float* ln_g       = (const float*)d_in[9];
    const float* ln_b       = (const float*)d_in[10];
    float* out = (float*)d_out;

    char* ws = (char*)d_ws;
    float*  xz      = (float*) (ws);                        // 64 MB [4096,4096]
    float*  dt      = (float*) (ws + ((size_t) 64 << 20));  // 32 MB [4096,2048]
    float*  xdbl    = (float*) (ws + ((size_t) 96 << 20));  //  2 MB [4096,128]
    ushort* xn_bf   = (ushort*)(ws + ((size_t) 98 << 20));  //  8 MB [4096,1024]
    ushort* Win_bf  = (ushort*)(ws + ((size_t)106 << 20));  //  8 MB (dead after GEMM1)
    ushort* y_bf    = (ushort*)(ws + ((size_t)106 << 20));  // 16 MB, overlaps Win_bf
    ushort* Wout_bf = (ushort*)(ws + ((size_t)122 << 20));  //  4 MB [1024,2048]

    cvt_bf16<<<(4096*1024/4 + 255)/256, 256, 0, stream>>>(W_in,  Win_bf,  4096*1024/4);
    cvt_bf16<<<(1024*2048/4 + 255)/256, 256, 0, stream>>>(W_out, Wout_bf, 1024*2048/4);
    // 1. LayerNorm -> bf16
    ln_kernel<<<BT, 256, 0, stream>>>(x, ln_g, ln_b, xn_bf);
    // 2. xz = xn @ W_in^T   [4096,4096]  (bf16 MFMA)
    gemm_bt_bf16<0><<<dim3(BT/128, 4096/128), 256, 0, stream>>>(
        xn_bf, Win_bf, xz, 4096, D_MODEL, nullptr);
    // 3. x_dbl = x_ssm @ W_x^T   [4096,128]  (fp32)
    gemm_nt<0><<<dim3(BT/64, 128/64), 256, 0, stream>>>(
        xz, 4096, W_x, D_INNER, xdbl, 128, D_INNER, nullptr);
    // 4. dt = softplus(dt_low @ W_dt^T + b_dt)   [4096,2048]  (fp32)
    gemm_nt<1><<<dim3(BT/64, D_INNER/64), 256, 0, stream>>>(
        xdbl, 128, W_dt, DT_RANK, dt, D_INNER, DT_RANK, b_dt);
    // 5. scan -> raw p (bf16)
    scan_kernel<<<512, 256, 0, stream>>>(xz, xdbl, dt, A_log_real, A_imag, y_bf);
    // 5b. gating in-place
    gate_kernel<<<4096*512/256, 256, 0, stream>>>(y_bf, xz, D_param);
    // 6. out = residual + y @ W_out^T   [4096,1024]  (bf16 MFMA + resid)
    gemm_bt_bf16<1><<<dim3(BT/128, D_MODEL/128), 256, 0, stream>>>(
        y_bf, Wout_bf, out, D_MODEL, D_INNER, x);
}

// Round 4
// 581.000 us; speedup vs baseline: 3.9266x; 1.5712x over previous
//
#include <hip/hip_runtime.h>
#include <math.h>

#define D_MODEL 1024
#define D_STATE 32
#define D_INNER 2048
#define DT_RANK 64
#define BT 4096            // B*T = 2*2048
#define LN_EPS 1e-5f

typedef __attribute__((ext_vector_type(8))) short short8;
typedef __attribute__((ext_vector_type(4))) float f32x4;
typedef const __attribute__((address_space(1))) void* gp_t;
typedef __attribute__((address_space(3))) void* lp_t;

__device__ __forceinline__ ushort bf16r(float f) {
    unsigned u = __float_as_uint(f);
    u += 0x7fff + ((u >> 16) & 1);          // round-to-nearest-even
    return (ushort)(u >> 16);
}

// ---------------------------------------------------------------- fp32 -> bf16
__global__ __launch_bounds__(256) void cvt_bf16(const float* __restrict__ in,
                                                ushort* __restrict__ out, int n4) {
    int i = blockIdx.x * 256 + threadIdx.x;
    if (i >= n4) return;
    float4 v = ((const float4*)in)[i];
    ushort4 o;
    o.x = bf16r(v.x); o.y = bf16r(v.y); o.z = bf16r(v.z); o.w = bf16r(v.w);
    ((ushort4*)out)[i] = o;
}

// ---------------------------------------------------------------- LayerNorm -> bf16
__global__ __launch_bounds__(256) void ln_kernel(const float* __restrict__ x,
                                                 const float* __restrict__ g,
                                                 const float* __restrict__ b,
                                                 ushort* __restrict__ xn) {
    int row = blockIdx.x;
    const float4* xr = (const float4*)(x + (size_t)row * D_MODEL);
    float4 v = xr[threadIdx.x];
    float s  = v.x + v.y + v.z + v.w;
    float ss = v.x*v.x + v.y*v.y + v.z*v.z + v.w*v.w;
    #pragma unroll
    for (int off = 32; off > 0; off >>= 1) {
        s  += __shfl_down(s,  off, 64);
        ss += __shfl_down(ss, off, 64);
    }
    __shared__ float rs[4], rss[4];
    int wave = threadIdx.x >> 6;
    if ((threadIdx.x & 63) == 0) { rs[wave] = s; rss[wave] = ss; }
    __syncthreads();
    s  = rs[0] + rs[1] + rs[2] + rs[3];
    ss = rss[0] + rss[1] + rss[2] + rss[3];
    float mu  = s * (1.f / D_MODEL);
    float var = ss * (1.f / D_MODEL) - mu * mu;
    float inv = rsqrtf(var + LN_EPS);
    float4 gv = ((const float4*)g)[threadIdx.x];
    float4 bv = ((const float4*)b)[threadIdx.x];
    ushort4 o;
    o.x = bf16r((v.x - mu) * inv * gv.x + bv.x);
    o.y = bf16r((v.y - mu) * inv * gv.y + bv.y);
    o.z = bf16r((v.z - mu) * inv * gv.z + bv.z);
    o.w = bf16r((v.w - mu) * inv * gv.w + bv.w);
    ((ushort4*)(xn + (size_t)row * D_MODEL))[threadIdx.x] = o;
}

// ------------------------------------------------- bf16 MFMA NT GEMM (m97-style)
// C[M,N] = A[M,K] * B[N,K]^T (+resid). 128x128 tile, BK=32, 256 thr = 4 waves.
// Staging via global_load_lds width=16: LDS dest = wave_base + lane*16,
// which matches the dense [m][k] tile layout exactly.
template<int RESID>
__global__ __launch_bounds__(256) void gemm_bt_bf16(
    const ushort* __restrict__ A, const ushort* __restrict__ B,
    float* __restrict__ C, int ldc, int K,
    const float* __restrict__ resid)
{
    __shared__ __align__(16) ushort As[128 * 32];   // [m][k] dense
    __shared__ __align__(16) ushort Bs[128 * 32];   // [n][k] dense
    int tid = threadIdx.x;
    int bm = blockIdx.x * 128, bn = blockIdx.y * 128;
    int wave = tid >> 6, lane = tid & 63;
    int wm = (wave & 1) * 64, wn = (wave >> 1) * 64;
    int quad = lane >> 4, m16 = lane & 15;
    int grow = tid >> 2;              // 0..63
    int gcol = (tid & 3) * 8;         // k-elem offset
    const size_t a0 = (size_t)(bm + grow) * K + gcol;
    const size_t b0 = (size_t)(bn + grow) * K + gcol;
    char* asw = (char*)As + wave * 1024;   // wave-uniform LDS base
    char* bsw = (char*)Bs + wave * 1024;

    f32x4 acc[4][4] = {};
    for (int k0 = 0; k0 < K; k0 += 32) {
        __builtin_amdgcn_global_load_lds((gp_t)(A + a0 + k0),                 (lp_t)asw,          16, 0, 0);
        __builtin_amdgcn_global_load_lds((gp_t)(A + a0 + (size_t)64*K + k0),  (lp_t)(asw + 4096), 16, 0, 0);
        __builtin_amdgcn_global_load_lds((gp_t)(B + b0 + k0),                 (lp_t)bsw,          16, 0, 0);
        __builtin_amdgcn_global_load_lds((gp_t)(B + b0 + (size_t)64*K + k0),  (lp_t)(bsw + 4096), 16, 0, 0);
        __syncthreads();
        short8 af[4], bf[4];
        #pragma unroll
        for (int i = 0; i < 4; ++i)
            af[i] = *(const short8*)&As[(wm + i * 16 + m16) * 32 + quad * 8];
        #pragma unroll
        for (int j = 0; j < 4; ++j)
            bf[j] = *(const short8*)&Bs[(wn + j * 16 + m16) * 32 + quad * 8];
        #pragma unroll
        for (int i = 0; i < 4; ++i)
            #pragma unroll
            for (int j = 0; j < 4; ++j)
                acc[i][j] = __builtin_amdgcn_mfma_f32_16x16x32_bf16(
                    af[i], bf[j], acc[i][j], 0, 0, 0);
        __syncthreads();
    }
    #pragma unroll
    for (int i = 0; i < 4; ++i) {
        #pragma unroll
        for (int r = 0; r < 4; ++r) {
            int row = bm + wm + i * 16 + quad * 4 + r;
            #pragma unroll
            for (int j = 0; j < 4; ++j) {
                int col = bn + wn + j * 16 + m16;
                float v = acc[i][j][r];
                if (RESID) v += resid[(size_t)row * ldc + col];
                C[(size_t)row * ldc + col] = v;
            }
        }
    }
}

// ------------------------------------------------- generic fp32 NT GEMM (small ops)
template<int ACT>
__global__ __launch_bounds__(256) void gemm_nt(const float* __restrict__ A, int lda,
                                               const float* __restrict__ B, int ldb,
                                               float* __restrict__ C, int ldc,
                                               int K,
                                               const float* __restrict__ bias) {
    __shared__ float As[16][68];
    __shared__ float Bs[16][68];
    int tid = threadIdx.x;
    int bm = blockIdx.x * 64;
    int bn = blockIdx.y * 64;
    int tx = tid & 15, ty = tid >> 4;
    int lr = tid >> 2;
    int lk = (tid & 3) << 2;
    const float* Ap = A + (size_t)(bm + lr) * lda + lk;
    const float* Bp = B + (size_t)(bn + lr) * ldb + lk;
    float acc[4][4] = {};
    for (int k0 = 0; k0 < K; k0 += 16) {
        float4 a4 = *(const float4*)(Ap + k0);
        float4 b4 = *(const float4*)(Bp + k0);
        As[lk+0][lr] = a4.x; As[lk+1][lr] = a4.y; As[lk+2][lr] = a4.z; As[lk+3][lr] = a4.w;
        Bs[lk+0][lr] = b4.x; Bs[lk+1][lr] = b4.y; Bs[lk+2][lr] = b4.z; Bs[lk+3][lr] = b4.w;
        __syncthreads();
        #pragma unroll
        for (int k = 0; k < 16; ++k) {
            float4 av = *(const float4*)&As[k][ty << 2];
            float4 bv = *(const float4*)&Bs[k][tx << 2];
            float ar[4] = {av.x, av.y, av.z, av.w};
            float br[4] = {bv.x, bv.y, bv.z, bv.w};
            #pragma unroll
            for (int i = 0; i < 4; ++i)
                #pragma unroll
                for (int j = 0; j < 4; ++j)
                    acc[i][j] = fmaf(ar[i], br[j], acc[i][j]);
        }
        __syncthreads();
    }
    #pragma unroll
    for (int i = 0; i < 4; ++i) {
        int row = bm + (ty << 2) + i;
        #pragma unroll
        for (int j = 0; j < 4; ++j) {
            int col = bn + (tx << 2) + j;
            float v = acc[i][j];
            if (bias)  v += bias[col];
            if (ACT == 1) v = (v > 20.f) ? v : __logf(1.f + __expf(v));
            C[(size_t)row * ldc + col] = v;
        }
    }
}

// ---------------------------------------------------------------- scan v4
// Chunk-staged (32 t), double-buffered LDS. Block 256 = 8 e x 32 s, grid 512.
// Reduction over s via wave-private LDS transpose tile (no shuffle chain on
// the critical path). Gating fused at reduce time. Output gated y in bf16.
__global__ __launch_bounds__(256) void scan_kernel(
    const float* __restrict__ xz,     // [BT, 4096]  (x_ssm | z)
    const float* __restrict__ xdbl,   // [BT, 128]   (dt_low | B | C)
    const float* __restrict__ dtm,    // [BT, 2048]
    const float* __restrict__ A_log_real,
    const float* __restrict__ A_imag,
    const float* __restrict__ D_param,
    ushort* __restrict__ y)           // [BT, 2048] bf16 (gated)
{
    const int tid = threadIdx.x;
    const int s   = tid & 31;
    const int el  = tid >> 5;                  // 0..7
    const int b   = blockIdx.x >> 8;
    const int e0  = (blockIdx.x & 255) << 3;
    const int e   = e0 + el;
    const int stt = tid >> 3;                  // 0..31 (t row for d/x/z staging)
    const int sk  = tid & 7;                   // 0..7  (e for d/x/z staging)
    const int btt = tid >> 4;                  // 0..15 (t row for B/C staging)
    const int bk  = (tid & 15) << 2;           // 0..60 (col for B/C staging)

    __shared__ __align__(16) float dxz[2][8][32][4];  // [e][t]{dt,x,z,pad}  8 KB
    __shared__ __align__(16) float bcs[2][32][64];    // [t][B(32)|C(32)]   16 KB
    __shared__ __align__(16) float red[8][32][36];    // wave-private tiles 36 KB

    const float Ar = -__expf(A_log_real[e * D_STATE + s]);
    const float Ai = A_imag[e * D_STATE + s];
    const float Dp = D_param[e];
    float hr = 0.f, hi = 0.f;
    const float* xzb = xz   + (size_t)b * 2048 * 4096;
    const float* xdb = xdbl + (size_t)b * 2048 * 128;
    const float* dtb = dtm  + (size_t)b * 2048 * 2048;
    ushort*      yb  = y    + (size_t)b * 2048 * 2048;

    float r_d, r_x, r_z;
    float4 r_bc0, r_bc1;
    {   // prologue: chunk 0
        r_d = dtb[(size_t)stt * 2048 + e0 + sk];
        r_x = xzb[(size_t)stt * 4096 + e0 + sk];
        r_z = xzb[(size_t)stt * 4096 + 2048 + e0 + sk];
        r_bc0 = *(const float4*)&xdb[(size_t)btt * 128 + DT_RANK + bk];
        r_bc1 = *(const float4*)&xdb[(size_t)(btt + 16) * 128 + DT_RANK + bk];
        dxz[0][sk][stt][0] = r_d; dxz[0][sk][stt][1] = r_x; dxz[0][sk][stt][2] = r_z;
        *(float4*)&bcs[0][btt][bk]      = r_bc0;
        *(float4*)&bcs[0][btt + 16][bk] = r_bc1;
    }
    for (int c = 0; c < 64; ++c) {
        const int buf = c & 1;
        __syncthreads();
        if (c < 63) {               // prefetch next chunk into registers
            const int tn = (c + 1) * 32;
            r_d = dtb[(size_t)(tn + stt) * 2048 + e0 + sk];
            r_x = xzb[(size_t)(tn + stt) * 4096 + e0 + sk];
            r_z = xzb[(size_t)(tn + stt) * 4096 + 2048 + e0 + sk];
            r_bc0 = *(const float4*)&xdb[(size_t)(tn + btt) * 128 + DT_RANK + bk];
            r_bc1 = *(const float4*)&xdb[(size_t)(tn + btt + 16) * 128 + DT_RANK + bk];
        }
        #pragma unroll 8
        for (int tt = 0; tt < 32; ++tt) {
            float4 dxv = *(const float4*)&dxz[buf][el][tt][0];   // broadcast
            float Bv = bcs[buf][tt][s];
            float Cv = bcs[buf][tt][32 + s];
            float dtv = dxv.x, xv = dxv.y;
            float sc  = __expf(Ar * dtv);
            float ang = Ai * dtv;
            float sa = __sinf(ang), ca = __cosf(ang);
            float dAr = sc * ca, dAi = sc * sa;
            float dBx = dtv * xv * Bv;
            float hr2 = dAr * hr - dAi * hi + dBx;
            hi = dAr * hi + dAi * hr;
            hr = hr2;
            red[el][tt][s] = hr * Cv;                            // transpose tile
        }
        // lane s sums tile row t=s (wave-private, in-order DS: no barrier)
        float acc = 0.f;
        #pragma unroll
        for (int k = 0; k < 8; ++k) {
            float4 v = *(const float4*)&red[el][s][k * 4];
            acc += (v.x + v.y) + (v.z + v.w);
        }
        float xg = dxz[buf][el][s][1];
        float zg = dxz[buf][el][s][2];
        float sig = 1.f / (1.f + __expf(-zg));
        float yv  = (acc + Dp * xg) * zg * sig;
        yb[(size_t)(c * 32 + s) * 2048 + e] = bf16r(yv);
        if (c < 63) {
            const int nb = buf ^ 1;
            dxz[nb][sk][stt][0] = r_d; dxz[nb][sk][stt][1] = r_x; dxz[nb][sk][stt][2] = r_z;
            *(float4*)&bcs[nb][btt][bk]      = r_bc0;
            *(float4*)&bcs[nb][btt + 16][bk] = r_bc1;
        }
    }
}

// ---------------------------------------------------------------- launch
extern "C" void kernel_launch(void* const* d_in, const int* in_sizes, int n_in,
                              void* d_out, int out_size, void* d_ws, size_t ws_size,
                              hipStream_t stream) {
    const float* x          = (const float*)d_in[0];
    const float* W_in       = (const float*)d_in[1];
    const float* W_x        = (const float*)d_in[2];
    const float* W_dt       = (const float*)d_in[3];
    const float* b_dt       = (const float*)d_in[4];
    const float* A_log_real = (const float*)d_in[5];
    const float* A_imag     = (const float*)d_in[6];
    const float* D_param    = (const float*)d_in[7];
    const float* W_out      = (const float*)d_in[8];
    const float* ln_g       = (const float*)d_in[9];
    const float* ln_b       = (const float*)d_in[10];
    float* out = (float*)d_out;

    char* ws = (char*)d_ws;
    float*  xz      = (float*) (ws);                        // 64 MB [4096,4096]
    float*  dt      = (float*) (ws + ((size_t) 64 << 20));  // 32 MB [4096,2048]
    float*  xdbl    = (float*) (ws + ((size_t) 96 << 20));  //  2 MB [4096,128]
    ushort* xn_bf   = (ushort*)(ws + ((size_t) 98 << 20));  //  8 MB [4096,1024]
    ushort* Win_bf  = (ushort*)(ws + ((size_t)106 << 20));  //  8 MB (dead after GEMM1)
    ushort* y_bf    = (ushort*)(ws + ((size_t)106 << 20));  // 16 MB, overlaps Win_bf
    ushort* Wout_bf = (ushort*)(ws + ((size_t)122 << 20));  //  4 MB [1024,2048]

    cvt_bf16<<<(4096*1024/4 + 255)/256, 256, 0, stream>>>(W_in,  Win_bf,  4096*1024/4);
    cvt_bf16<<<(1024*2048/4 + 255)/256, 256, 0, stream>>>(W_out, Wout_bf, 1024*2048/4);
    // 1. LayerNorm -> bf16
    ln_kernel<<<BT, 256, 0, stream>>>(x, ln_g, ln_b, xn_bf);
    // 2. xz = xn @ W_in^T   [4096,4096]  (bf16 MFMA)
    gemm_bt_bf16<0><<<dim3(BT/128, 4096/128), 256, 0, stream>>>(
        xn_bf, Win_bf, xz, 4096, D_MODEL, nullptr);
    // 3. x_dbl = x_ssm @ W_x^T   [4096,128]  (fp32)
    gemm_nt<0><<<dim3(BT/64, 128/64), 256, 0, stream>>>(
        xz, 4096, W_x, D_INNER, xdbl, 128, D_INNER, nullptr);
    // 4. dt = softplus(dt_low @ W_dt^T + b_dt)   [4096,2048]  (fp32)
    gemm_nt<1><<<dim3(BT/64, D_INNER/64), 256, 0, stream>>>(
        xdbl, 128, W_dt, DT_RANK, dt, D_INNER, DT_RANK, b_dt);
    // 5. scan + fused gating -> y (bf16)
    scan_kernel<<<512, 256, 0, stream>>>(xz, xdbl, dt, A_log_real, A_imag,
                                         D_param, y_bf);
    // 6. out = residual + y @ W_out^T   [4096,1024]  (bf16 MFMA + resid)
    gemm_bt_bf16<1><<<dim3(BT/128, D_MODEL/128), 256, 0, stream>>>(
        y_bf, Wout_bf, out, D_MODEL, D_INNER, x);
}

// Round 5
// 509.732 us; speedup vs baseline: 4.4755x; 1.1398x over previous
//
#include <hip/hip_runtime.h>
#include <math.h>

#define D_MODEL 1024
#define D_STATE 32
#define D_INNER 2048
#define DT_RANK 64
#define BT 4096            // B*T = 2*2048
#define XZLD 4224          // xz_aug row stride (4096 + 128)
#define LN_EPS 1e-5f

typedef __attribute__((ext_vector_type(8))) short short8;
typedef __attribute__((ext_vector_type(4))) float f32x4;
typedef const __attribute__((address_space(1))) void* gp_t;
typedef __attribute__((address_space(3))) void* lp_t;

__device__ __forceinline__ ushort bf16r(float f) {
    unsigned u = __float_as_uint(f);
    u += 0x7fff + ((u >> 16) & 1);          // round-to-nearest-even
    return (ushort)(u >> 16);
}

// ---------------------------------------------------------------- fp32 -> bf16
__global__ __launch_bounds__(256) void cvt_bf16(const float* __restrict__ in,
                                                ushort* __restrict__ out, int n4) {
    int i = blockIdx.x * 256 + threadIdx.x;
    if (i >= n4) return;
    float4 v = ((const float4*)in)[i];
    ushort4 o;
    o.x = bf16r(v.x); o.y = bf16r(v.y); o.z = bf16r(v.z); o.w = bf16r(v.w);
    ((ushort4*)out)[i] = o;
}

// ---------------------------------------------------------------- transpose + cvt
// in: fp32 [2048,1024] (rows e, cols d) -> out: bf16 [1024,2048] (rows d, cols e)
__global__ __launch_bounds__(256) void transpose_cvt(const float* __restrict__ in,
                                                     ushort* __restrict__ out) {
    __shared__ float tile[32][33];
    int bx = blockIdx.x * 32;   // e base
    int by = blockIdx.y * 32;   // d base
    int tx = threadIdx.x & 31, ty = threadIdx.x >> 5;   // ty 0..7
    #pragma unroll
    for (int i = 0; i < 32; i += 8)
        tile[ty + i][tx] = in[(size_t)(bx + ty + i) * 1024 + by + tx];
    __syncthreads();
    #pragma unroll
    for (int i = 0; i < 32; i += 8)
        out[(size_t)(by + ty + i) * 2048 + bx + tx] = bf16r(tile[tx][ty + i]);
}

// ---------------------------------------------------------------- LayerNorm -> bf16
__global__ __launch_bounds__(256) void ln_kernel(const float* __restrict__ x,
                                                 const float* __restrict__ g,
                                                 const float* __restrict__ b,
                                                 ushort* __restrict__ xn) {
    int row = blockIdx.x;
    const float4* xr = (const float4*)(x + (size_t)row * D_MODEL);
    float4 v = xr[threadIdx.x];
    float s  = v.x + v.y + v.z + v.w;
    float ss = v.x*v.x + v.y*v.y + v.z*v.z + v.w*v.w;
    #pragma unroll
    for (int off = 32; off > 0; off >>= 1) {
        s  += __shfl_down(s,  off, 64);
        ss += __shfl_down(ss, off, 64);
    }
    __shared__ float rs[4], rss[4];
    int wave = threadIdx.x >> 6;
    if ((threadIdx.x & 63) == 0) { rs[wave] = s; rss[wave] = ss; }
    __syncthreads();
    s  = rs[0] + rs[1] + rs[2] + rs[3];
    ss = rss[0] + rss[1] + rss[2] + rss[3];
    float mu  = s * (1.f / D_MODEL);
    float var = ss * (1.f / D_MODEL) - mu * mu;
    float inv = rsqrtf(var + LN_EPS);
    float4 gv = ((const float4*)g)[threadIdx.x];
    float4 bv = ((const float4*)b)[threadIdx.x];
    ushort4 o;
    o.x = bf16r((v.x - mu) * inv * gv.x + bv.x);
    o.y = bf16r((v.y - mu) * inv * gv.y + bv.y);
    o.z = bf16r((v.z - mu) * inv * gv.z + bv.z);
    o.w = bf16r((v.w - mu) * inv * gv.w + bv.w);
    ((ushort4*)(xn + (size_t)row * D_MODEL))[threadIdx.x] = o;
}

// ------------------------------------------------- bf16 MFMA NT GEMM (m97-style)
template<int RESID>
__global__ __launch_bounds__(256) void gemm_bt_bf16(
    const ushort* __restrict__ A, const ushort* __restrict__ B,
    float* __restrict__ C, int ldc, int K,
    const float* __restrict__ resid)
{
    __shared__ __align__(16) ushort As[128 * 32];   // [m][k] dense
    __shared__ __align__(16) ushort Bs[128 * 32];   // [n][k] dense
    int tid = threadIdx.x;
    int bm = blockIdx.x * 128, bn = blockIdx.y * 128;
    int wave = tid >> 6, lane = tid & 63;
    int wm = (wave & 1) * 64, wn = (wave >> 1) * 64;
    int quad = lane >> 4, m16 = lane & 15;
    int grow = tid >> 2;
    int gcol = (tid & 3) * 8;
    const size_t a0 = (size_t)(bm + grow) * K + gcol;
    const size_t b0 = (size_t)(bn + grow) * K + gcol;
    char* asw = (char*)As + wave * 1024;
    char* bsw = (char*)Bs + wave * 1024;

    f32x4 acc[4][4] = {};
    for (int k0 = 0; k0 < K; k0 += 32) {
        __builtin_amdgcn_global_load_lds((gp_t)(A + a0 + k0),                 (lp_t)asw,          16, 0, 0);
        __builtin_amdgcn_global_load_lds((gp_t)(A + a0 + (size_t)64*K + k0),  (lp_t)(asw + 4096), 16, 0, 0);
        __builtin_amdgcn_global_load_lds((gp_t)(B + b0 + k0),                 (lp_t)bsw,          16, 0, 0);
        __builtin_amdgcn_global_load_lds((gp_t)(B + b0 + (size_t)64*K + k0),  (lp_t)(bsw + 4096), 16, 0, 0);
        __syncthreads();
        short8 af[4], bf[4];
        #pragma unroll
        for (int i = 0; i < 4; ++i)
            af[i] = *(const short8*)&As[(wm + i * 16 + m16) * 32 + quad * 8];
        #pragma unroll
        for (int j = 0; j < 4; ++j)
            bf[j] = *(const short8*)&Bs[(wn + j * 16 + m16) * 32 + quad * 8];
        #pragma unroll
        for (int i = 0; i < 4; ++i)
            #pragma unroll
            for (int j = 0; j < 4; ++j)
                acc[i][j] = __builtin_amdgcn_mfma_f32_16x16x32_bf16(
                    af[i], bf[j], acc[i][j], 0, 0, 0);
        __syncthreads();
    }
    #pragma unroll
    for (int i = 0; i < 4; ++i) {
        #pragma unroll
        for (int r = 0; r < 4; ++r) {
            int row = bm + wm + i * 16 + quad * 4 + r;
            #pragma unroll
            for (int j = 0; j < 4; ++j) {
                int col = bn + wn + j * 16 + m16;
                float v = acc[i][j][r];
                if (RESID) v += resid[(size_t)row * ldc + col];
                C[(size_t)row * ldc + col] = v;
            }
        }
    }
}

// ------------------------------------------------- generic fp32 NT GEMM (GEMM3)
template<int ACT>
__global__ __launch_bounds__(256) void gemm_nt(const float* __restrict__ A, int lda,
                                               const float* __restrict__ B, int ldb,
                                               float* __restrict__ C, int ldc,
                                               int K,
                                               const float* __restrict__ bias) {
    __shared__ float As[16][68];
    __shared__ float Bs[16][68];
    int tid = threadIdx.x;
    int bm = blockIdx.x * 64;
    int bn = blockIdx.y * 64;
    int tx = tid & 15, ty = tid >> 4;
    int lr = tid >> 2;
    int lk = (tid & 3) << 2;
    const float* Ap = A + (size_t)(bm + lr) * lda + lk;
    const float* Bp = B + (size_t)(bn + lr) * ldb + lk;
    float acc[4][4] = {};
    for (int k0 = 0; k0 < K; k0 += 16) {
        float4 a4 = *(const float4*)(Ap + k0);
        float4 b4 = *(const float4*)(Bp + k0);
        As[lk+0][lr] = a4.x; As[lk+1][lr] = a4.y; As[lk+2][lr] = a4.z; As[lk+3][lr] = a4.w;
        Bs[lk+0][lr] = b4.x; Bs[lk+1][lr] = b4.y; Bs[lk+2][lr] = b4.z; Bs[lk+3][lr] = b4.w;
        __syncthreads();
        #pragma unroll
        for (int k = 0; k < 16; ++k) {
            float4 av = *(const float4*)&As[k][ty << 2];
            float4 bv = *(const float4*)&Bs[k][tx << 2];
            float ar[4] = {av.x, av.y, av.z, av.w};
            float br[4] = {bv.x, bv.y, bv.z, bv.w};
            #pragma unroll
            for (int i = 0; i < 4; ++i)
                #pragma unroll
                for (int j = 0; j < 4; ++j)
                    acc[i][j] = fmaf(ar[i], br[j], acc[i][j]);
        }
        __syncthreads();
    }
    #pragma unroll
    for (int i = 0; i < 4; ++i) {
        int row = bm + (ty << 2) + i;
        #pragma unroll
        for (int j = 0; j < 4; ++j) {
            int col = bn + (tx << 2) + j;
            float v = acc[i][j];
            if (bias)  v += bias[col];
            if (ACT == 1) v = (v > 20.f) ? v : __logf(1.f + __expf(v));
            C[(size_t)row * ldc + col] = v;
        }
    }
}

// ---------------------------------------------------------------- scan v5
// Chunk-staged (32 t), double-buffered LDS. Block 256 = 8 e x 32 s, grid 512.
// Reduction via XOR-swizzled wave-private LDS tile. Gating fused.
__global__ __launch_bounds__(256) void scan_kernel(
    const float* __restrict__ xz,     // [BT, 4224]  (x_ssm | z | dt_low,B,C)
    const float* __restrict__ dtm,    // [BT, 2048]
    const float* __restrict__ A_log_real,
    const float* __restrict__ A_imag,
    const float* __restrict__ D_param,
    ushort* __restrict__ y)           // [BT, 2048] bf16 (gated)
{
    const int tid = threadIdx.x;
    const int s   = tid & 31;
    const int el  = tid >> 5;                  // 0..7
    const int b   = blockIdx.x >> 8;
    const int e0  = (blockIdx.x & 255) << 3;
    const int e   = e0 + el;
    const int stt = tid >> 3;                  // 0..31 (t row for d/x/z staging)
    const int sk  = tid & 7;                   // 0..7  (e for d/x/z staging)
    const int btt = tid >> 4;                  // 0..15 (t row for B/C staging)
    const int bk  = (tid & 15) << 2;           // 0..60 (col for B/C staging)

    __shared__ __align__(16) float dxz[2][8][32][4];  // [e][t]{dt,-,x,z}    8 KB
    __shared__ __align__(16) float bcs[2][32][64];    // [t][B(32)|C(32)]   16 KB
    __shared__ __align__(16) float red[8][32][32];    // swizzled tiles     32 KB

    const float Ar   = -__expf(A_log_real[e * D_STATE + s]);
    const float Ai2p = A_imag[e * D_STATE + s] * 0.15915494f;   // /(2*pi)
    const float Dp   = D_param[e];
    float hr = 0.f, hi = 0.f;
    const float* xzb = xz + (size_t)b * 2048 * XZLD;
    const float* bcb = xzb + 4096 + DT_RANK;          // B/C columns base
    const float* dtb = dtm + (size_t)b * 2048 * 2048;
    ushort*      yb  = y   + (size_t)b * 2048 * 2048;
    const int sx4 = (s & 7) << 2;

    float r_d, r_x, r_z;
    float4 r_bc0, r_bc1;
    {   // prologue: chunk 0
        r_d = dtb[(size_t)stt * 2048 + e0 + sk];
        r_x = xzb[(size_t)stt * XZLD + e0 + sk];
        r_z = xzb[(size_t)stt * XZLD + 2048 + e0 + sk];
        r_bc0 = *(const float4*)&bcb[(size_t)btt * XZLD + bk];
        r_bc1 = *(const float4*)&bcb[(size_t)(btt + 16) * XZLD + bk];
        dxz[0][sk][stt][0] = r_d; dxz[0][sk][stt][2] = r_x; dxz[0][sk][stt][3] = r_z;
        *(float4*)&bcs[0][btt][bk]      = r_bc0;
        *(float4*)&bcs[0][btt + 16][bk] = r_bc1;
    }
    for (int c = 0; c < 64; ++c) {
        const int buf = c & 1;
        __syncthreads();
        if (c < 63) {               // prefetch next chunk into registers
            const int tn = (c + 1) * 32;
            r_d = dtb[(size_t)(tn + stt) * 2048 + e0 + sk];
            r_x = xzb[(size_t)(tn + stt) * XZLD + e0 + sk];
            r_z = xzb[(size_t)(tn + stt) * XZLD + 2048 + e0 + sk];
            r_bc0 = *(const float4*)&bcb[(size_t)(tn + btt) * XZLD + bk];
            r_bc1 = *(const float4*)&bcb[(size_t)(tn + btt + 16) * XZLD + bk];
        }
        #pragma unroll 8
        for (int tt = 0; tt < 32; ++tt) {
            float4 dxv = *(const float4*)&dxz[buf][el][tt][0];   // broadcast
            float Bv = bcs[buf][tt][s];
            float Cv = bcs[buf][tt][32 + s];
            float dtv = dxv.x, xv = dxv.z;
            float sc = __expf(Ar * dtv);
            float u  = Ai2p * dtv;
            float sa = __builtin_amdgcn_sinf(u);
            float ca = __builtin_amdgcn_cosf(u);
            float dAr = sc * ca, dAi = sc * sa;
            float dBx = (dtv * xv) * Bv;
            float hr2 = dAr * hr - dAi * hi + dBx;
            hi = dAr * hi + dAi * hr;
            hr = hr2;
            red[el][tt][s ^ ((tt & 7) << 2)] = hr * Cv;   // swizzled store
        }
        // lane s sums tile row t=s (wave-private, in-order DS: no barrier)
        float acc = 0.f;
        #pragma unroll
        for (int p = 0; p < 8; ++p) {
            float4 v = *(const float4*)&red[el][s][(p << 2) ^ sx4];
            acc += (v.x + v.y) + (v.z + v.w);
        }
        float2 xzg = *(const float2*)&dxz[buf][el][s][2];   // {x, z}
        float sig = 1.f / (1.f + __expf(-xzg.y));
        yb[(size_t)(c * 32 + s) * 2048 + e] = bf16r((acc + Dp * xzg.x) * xzg.y * sig);
        if (c < 63) {
            const int nb = buf ^ 1;
            dxz[nb][sk][stt][0] = r_d; dxz[nb][sk][stt][2] = r_x; dxz[nb][sk][stt][3] = r_z;
            *(float4*)&bcs[nb][btt][bk]      = r_bc0;
            *(float4*)&bcs[nb][btt + 16][bk] = r_bc1;
        }
    }
}

// ---------------------------------------------------------------- launch
extern "C" void kernel_launch(void* const* d_in, const int* in_sizes, int n_in,
                              void* d_out, int out_size, void* d_ws, size_t ws_size,
                              hipStream_t stream) {
    const float* x          = (const float*)d_in[0];
    const float* W_in       = (const float*)d_in[1];
    const float* W_x        = (const float*)d_in[2];
    const float* W_dt       = (const float*)d_in[3];
    const float* b_dt       = (const float*)d_in[4];
    const float* A_log_real = (const float*)d_in[5];
    const float* A_imag     = (const float*)d_in[6];
    const float* D_param    = (const float*)d_in[7];
    const float* W_out      = (const float*)d_in[8];
    const float* ln_g       = (const float*)d_in[9];
    const float* ln_b       = (const float*)d_in[10];
    float* out = (float*)d_out;

    char* ws = (char*)d_ws;
    float*  xz      = (float*) (ws);                        // 66 MiB [4096,4224]
    float*  dt      = (float*) (ws + ((size_t) 66 << 20));  // 32 MiB [4096,2048]
    ushort* xn_bf   = (ushort*)(ws + ((size_t) 98 << 20));  //  8 MiB [4096,1024]
    ushort* Waug    = (ushort*)(ws + ((size_t)106 << 20));  //  8.25 MiB [4224,1024]
    ushort* y_bf    = (ushort*)(ws + ((size_t)115 << 20));  // 16 MiB [4096,2048]
    ushort* Wout_bf = (ushort*)(ws + ((size_t)131 << 20));  //  4 MiB [1024,2048]
    // transient prep buffers inside xz region (dead before GEMM1 writes xz)
    float*  Wcomb   = (float*) (ws);                        // 0.5 MiB [128,1024]
    ushort* Wx_bf   = (ushort*)(ws + ((size_t)  1 << 20));  // 0.5 MiB [128,2048]
    ushort* WinT_bf = (ushort*)(ws + ((size_t)  2 << 20));  //  4 MiB [1024,2048]

    // --- weight prep ---
    cvt_bf16<<<4096, 256, 0, stream>>>(W_in,  Waug,    4096*1024/4);
    cvt_bf16<<<2048, 256, 0, stream>>>(W_out, Wout_bf, 1024*2048/4);
    cvt_bf16<<< 256, 256, 0, stream>>>(W_x,   Wx_bf,    128*2048/4);
    transpose_cvt<<<dim3(64, 32), 256, 0, stream>>>(W_in, WinT_bf);
    // W_comb = W_x @ W_in_x  [128,1024]
    gemm_bt_bf16<0><<<dim3(1, 8), 256, 0, stream>>>(
        Wx_bf, WinT_bf, Wcomb, 1024, 2048, nullptr);
    cvt_bf16<<<128, 256, 0, stream>>>(Wcomb, Waug + (size_t)4096*1024, 128*1024/4);
    // --- main chain ---
    ln_kernel<<<BT, 256, 0, stream>>>(x, ln_g, ln_b, xn_bf);
    // GEMM1(aug): xz_aug = xn @ [W_in; W_comb]^T   [4096,4224]
    gemm_bt_bf16<0><<<dim3(BT/128, XZLD/128), 256, 0, stream>>>(
        xn_bf, Waug, xz, XZLD, D_MODEL, nullptr);
    // GEMM3: dt = softplus(dt_low @ W_dt^T + b_dt)  (dt_low = xz_aug[:,4096:4160])
    gemm_nt<1><<<dim3(BT/64, D_INNER/64), 256, 0, stream>>>(
        xz + 4096, XZLD, W_dt, DT_RANK, dt, D_INNER, DT_RANK, b_dt);
    // scan + fused gating -> y (bf16)
    scan_kernel<<<512, 256, 0, stream>>>(xz, dt, A_log_real, A_imag, D_param, y_bf);
    // GEMM4: out = residual + y @ W_out^T   [4096,1024]
    gemm_bt_bf16<1><<<dim3(BT/128, D_MODEL/128), 256, 0, stream>>>(
        y_bf, Wout_bf, out, D_MODEL, D_INNER, x);
}